// Round 4
// baseline (622.746 us; speedup 1.0000x reference)
//
#include <hip/hip_runtime.h>

#define DECAY 0.99f
#define OMD   0.01f
#define EPS   1e-5f

constexpr int Bb = 16, Ss = 2048, Dd = 512, Kk = 2048;
constexpr int Nn = Bb * Ss;  // 32768

typedef __attribute__((ext_vector_type(8))) short short8;
typedef __attribute__((ext_vector_type(4))) float f32x4;

__device__ __forceinline__ unsigned short f2bf(float x) {
    unsigned u = __float_as_uint(x);
    unsigned r = (u + 0x7FFFu + ((u >> 16) & 1u)) >> 16;   // RN-even
    return (unsigned short)r;
}
__device__ __forceinline__ float bf2f(unsigned short u) {
    return __uint_as_float((unsigned)u << 16);
}

__device__ __forceinline__ void gload_lds16(const void* g, void* l) {
    __builtin_amdgcn_global_load_lds(
        (const __attribute__((address_space(1))) void*)g,
        (__attribute__((address_space(3))) void*)l, 16, 0, 0);
}

#define BARF() do { asm volatile("" ::: "memory"); \
                    __builtin_amdgcn_s_barrier();  \
                    asm volatile("" ::: "memory"); } while (0)

// ---------------- row sum-of-squares ---------------------------------------
__global__ void rows_sq(const float* __restrict__ in, float* __restrict__ out, int nrows) {
    int row  = blockIdx.x * 4 + (threadIdx.x >> 6);
    int lane = threadIdx.x & 63;
    if (row >= nrows) return;
    const float4* p = (const float4*)(in + (size_t)row * Dd);
    float s = 0.f;
    #pragma unroll
    for (int i = 0; i < 2; ++i) {
        float4 v = p[lane + 64 * i];
        s += v.x * v.x + v.y * v.y + v.z * v.z + v.w * v.w;
    }
    #pragma unroll
    for (int off = 32; off; off >>= 1) s += __shfl_down(s, off);
    if (lane == 0) out[row] = s;
}

// ---------------- fp32 -> bf16x3 split -------------------------------------
__global__ void conv_split(const float* __restrict__ in,
                           unsigned short* __restrict__ ph,
                           unsigned short* __restrict__ pm,
                           unsigned short* __restrict__ pl, int n4) {
    int i = blockIdx.x * 256 + threadIdx.x;
    if (i >= n4) return;
    float4 v = ((const float4*)in)[i];
    float f[4] = {v.x, v.y, v.z, v.w};
    ushort4 h, m, l;
    unsigned short hh[4], mm[4], ll[4];
    #pragma unroll
    for (int j = 0; j < 4; ++j) {
        float x = f[j];
        unsigned short a = f2bf(x);  float ra = x - bf2f(a);
        unsigned short b = f2bf(ra); float rb = ra - bf2f(b);
        unsigned short c = f2bf(rb);
        hh[j] = a; mm[j] = b; ll[j] = c;
    }
    h.x = hh[0]; h.y = hh[1]; h.z = hh[2]; h.w = hh[3];
    m.x = mm[0]; m.y = mm[1]; m.z = mm[2]; m.w = mm[3];
    l.x = ll[0]; l.y = ll[1]; l.z = ll[2]; l.w = ll[3];
    ((ushort4*)ph)[i] = h;
    ((ushort4*)pm)[i] = m;
    ((ushort4*)pl)[i] = l;
}

// ---------------- bf16x3 MFMA GEMM, 256x256 tile, 8-phase / 2-K-tile iter --
// K_eff = 6*512 = 3072 -> 48 K-tiles of BK=64, 24 iters x 2 tiles.
// LDS slots [tile-parity][half][128][64] per operand (128 KB). One half-tile
// staged per phase into the just-died slot; waits vmcnt(6) only at ph3/ph7
// (stage->use lead 4-7 phases).
__global__ __launch_bounds__(512, 1) void gemm_split256(
    const unsigned short* __restrict__ xp,   // [3][Nn][512] bf16 planes
    const unsigned short* __restrict__ ep,   // [3][Kk][512]
    const float* __restrict__ xsq,
    const float* __restrict__ esq,
    float* __restrict__ dist,                // [Nn, Kk]
    unsigned long long* __restrict__ packed) // [Nn] argmax accumulator
{
    __shared__ unsigned short As[2][2][128][64];   // 64 KB
    __shared__ unsigned short Bs[2][2][128][64];   // 64 KB

    const int tid  = threadIdx.x;
    const int lane = tid & 63;
    const int wid  = tid >> 6;
    const int wr   = wid >> 2;   // 0..1
    const int wc   = wid & 3;    // 0..3

    // XCD-aware swizzle (nwg = 1024, divisible by 8 -> bijective)
    int bid = blockIdx.x;
    int wg  = (bid & 7) * 128 + (bid >> 3);
    int mb  = wg >> 3, nb = wg & 7;
    const int row0 = mb * 256, col0 = nb * 256;

    f32x4 acc[2][4][2][2] = {};
    short8 af[4][2], bf[2][2];

    const int l8   = lane >> 3;   // 0..7
    const int c8   = lane & 7;
    const int csrc = c8 ^ l8;     // pre-swizzled source chunk

    // part-plane schedule (6 products of bf16x3): A: h,h,m,m,h,l  B: h,m,h,m,l,h
    auto planeA = [&](int tt) -> const unsigned short* {
        const int AP[8] = {0, 0, 1, 1, 0, 2, 0, 0};
        return xp + (size_t)AP[(tt >> 3) & 7] * ((size_t)Nn * Dd);
    };
    auto planeB = [&](int tt) -> const unsigned short* {
        const int BP[8] = {0, 1, 0, 1, 2, 0, 0, 0};
        return ep + (size_t)BP[(tt >> 3) & 7] * ((size_t)Kk * Dd);
    };

    // stage half-tile h of K-tile tt into slot [d][h] (2 gloads/thread)
    auto stageA = [&](int d, int h, int tt) {
        const unsigned short* pl = planeA(tt);
        int ko = (tt & 7) * 64;
        #pragma unroll
        for (int jj = 0; jj < 2; ++jj) {
            int rowbase = jj * 64 + wid * 8;
            const unsigned short* src =
                pl + (size_t)(row0 + h * 128 + rowbase + l8) * Dd + ko + csrc * 8;
            gload_lds16(src, &As[d][h][rowbase][0]);
        }
    };
    auto stageB = [&](int d, int h, int tt) {
        const unsigned short* pl = planeB(tt);
        int ko = (tt & 7) * 64;
        #pragma unroll
        for (int jj = 0; jj < 2; ++jj) {
            int rowbase = jj * 64 + wid * 8;
            const unsigned short* src =
                pl + (size_t)(col0 + h * 128 + rowbase + l8) * Dd + ko + csrc * 8;
            gload_lds16(src, &Bs[d][h][rowbase][0]);
        }
    };

    auto readA = [&](int d, int mh) {
        #pragma unroll
        for (int m = 0; m < 4; ++m) {
            int r = wr * 64 + m * 16 + (lane & 15);
            #pragma unroll
            for (int ks = 0; ks < 2; ++ks) {
                int c = (ks * 4 + (lane >> 4)) ^ (r & 7);
                af[m][ks] = *(const short8*)&As[d][mh][r][c * 8];
            }
        }
    };
    auto readB = [&](int d, int nh) {
        #pragma unroll
        for (int n = 0; n < 2; ++n) {
            int r = wc * 32 + n * 16 + (lane & 15);
            #pragma unroll
            for (int ks = 0; ks < 2; ++ks) {
                int c = (ks * 4 + (lane >> 4)) ^ (r & 7);
                bf[n][ks] = *(const short8*)&Bs[d][nh][r][c * 8];
            }
        }
    };

    auto mfmaQ = [&](int mh, int nh) {
        __builtin_amdgcn_s_setprio(1);
        #pragma unroll
        for (int ks = 0; ks < 2; ++ks)
            #pragma unroll
            for (int m = 0; m < 4; ++m)
                #pragma unroll
                for (int n = 0; n < 2; ++n)
                    acc[mh][m][nh][n] =
                        __builtin_amdgcn_mfma_f32_16x16x32_bf16(af[m][ks], bf[n][ks],
                            acc[mh][m][nh][n], 0, 0, 0);
        __builtin_amdgcn_s_setprio(0);
    };

    // prologue: stage tiles 0,1 fully EXCEPT B[1][lo] (staged at ph0 of iter 0)
    stageA(0, 0, 0); stageB(0, 0, 0);
    stageB(0, 1, 0); stageA(0, 1, 0);
    stageA(1, 0, 1); stageB(1, 1, 1);
    stageA(1, 1, 1);
    asm volatile("s_waitcnt vmcnt(0)" ::: "memory");
    BARF();

    for (int i = 0; i < 24; ++i) {
        const int t1 = 2 * i + 1, u0 = 2 * i + 2, u1 = 2 * i + 3;
        // ph0: tile d=0, quad (0,0); stage B[1][lo] for THIS iter's t1
        readA(0, 0); readB(0, 0); stageB(1, 0, t1);
        BARF(); mfmaQ(0, 0); BARF();
        // ph1: quad (0,1); stage A[0][lo] for next iter
        readB(0, 1); stageA(0, 0, u0);
        BARF(); mfmaQ(0, 1); BARF();
        // ph2: quad (1,1); stage B[0][hi]'
        readA(0, 1); stageB(0, 1, u0);
        BARF(); mfmaQ(1, 1); BARF();
        // ph3: quad (1,0); stage A[0][hi]'
        readB(0, 0); stageA(0, 1, u0);
        BARF(); mfmaQ(1, 0);
        asm volatile("s_waitcnt vmcnt(6)" ::: "memory");
        BARF();
        // ph4: tile d=1, quad (0,0); stage B[0][lo]'
        readA(1, 0); readB(1, 0); stageB(0, 0, u0);
        BARF(); mfmaQ(0, 0); BARF();
        // ph5: quad (0,1); stage A[1][lo]'
        readB(1, 1); stageA(1, 0, u1);
        BARF(); mfmaQ(0, 1); BARF();
        // ph6: quad (1,1); stage B[1][hi]'
        readA(1, 1); stageB(1, 1, u1);
        BARF(); mfmaQ(1, 1); BARF();
        // ph7: quad (1,0); stage A[1][hi]'
        readB(1, 0); stageA(1, 1, u1);
        BARF(); mfmaQ(1, 0);
        asm volatile("s_waitcnt vmcnt(6)" ::: "memory");
        BARF();
    }
    asm volatile("s_waitcnt vmcnt(0)" ::: "memory");

    // epilogue: dist = 2*dot - xsq - esq ; fused per-row argmax
    const int jrow = (lane >> 4) * 4;
    const int ncol = lane & 15;
    #pragma unroll
    for (int mh = 0; mh < 2; ++mh) {
        #pragma unroll
        for (int m = 0; m < 4; ++m) {
            int rbase = row0 + mh * 128 + wr * 64 + m * 16 + jrow;
            #pragma unroll
            for (int j = 0; j < 4; ++j) {
                int row = rbase + j;
                float xs = xsq[row];
                float best = -3.4e38f; int bi = 0;
                #pragma unroll
                for (int nh = 0; nh < 2; ++nh) {
                    #pragma unroll
                    for (int n = 0; n < 2; ++n) {
                        int col = col0 + nh * 128 + wc * 32 + n * 16 + ncol;
                        float v = 2.f * acc[mh][m][nh][n][j] - xs - esq[col];
                        dist[(size_t)row * Kk + col] = v;
                        if (v > best) { best = v; bi = col; }
                    }
                }
                unsigned u = __float_as_uint(best);
                u = (u & 0x80000000u) ? ~u : (u | 0x80000000u);
                unsigned long long pk = ((unsigned long long)u << 32) | (unsigned)(~bi);
                #pragma unroll
                for (int off = 1; off < 16; off <<= 1) {
                    unsigned long long o = __shfl_xor(pk, off);
                    if (o > pk) pk = o;
                }
                if (ncol == 0) atomicMax(&packed[row], pk);
            }
        }
    }
}

__global__ void unpack_argmax(const unsigned long long* __restrict__ packed,
                              float* __restrict__ ind_f, int* __restrict__ ind_i) {
    int i = blockIdx.x * 256 + threadIdx.x;
    unsigned long long p = packed[i];
    int k = (int)(~(unsigned)(p & 0xFFFFFFFFull));
    ind_f[i] = (float)k;
    ind_i[i] = k;
}

// ---------------- OLD fp32 GEMM (fallback when ws too small) ---------------
#define BM 64
#define BN 64
#define BK 32
__global__ __launch_bounds__(256) void gemm_dist(
    const float* __restrict__ A, const float* __restrict__ Bm,
    const float* __restrict__ xsq, const float* __restrict__ esq,
    float* __restrict__ dist)
{
    __shared__ float Asl[BK][BM + 4];
    __shared__ float Bsl[BK][BN + 4];
    int tid = threadIdx.x;
    int row0 = blockIdx.x * BM, col0 = blockIdx.y * BN;
    int tx = tid & 15, ty = tid >> 4;
    float acc[4][4] = {};
    int lr = tid >> 3, lc = (tid & 7) * 4;
    for (int d0 = 0; d0 < Dd; d0 += BK) {
        float4 a0 = *(const float4*)(A  + (size_t)(row0 + lr)      * Dd + d0 + lc);
        float4 a1 = *(const float4*)(A  + (size_t)(row0 + lr + 32) * Dd + d0 + lc);
        float4 b0 = *(const float4*)(Bm + (size_t)(col0 + lr)      * Dd + d0 + lc);
        float4 b1 = *(const float4*)(Bm + (size_t)(col0 + lr + 32) * Dd + d0 + lc);
        __syncthreads();
        Asl[lc + 0][lr] = a0.x; Asl[lc + 1][lr] = a0.y; Asl[lc + 2][lr] = a0.z; Asl[lc + 3][lr] = a0.w;
        Asl[lc + 0][lr + 32] = a1.x; Asl[lc + 1][lr + 32] = a1.y; Asl[lc + 2][lr + 32] = a1.z; Asl[lc + 3][lr + 32] = a1.w;
        Bsl[lc + 0][lr] = b0.x; Bsl[lc + 1][lr] = b0.y; Bsl[lc + 2][lr] = b0.z; Bsl[lc + 3][lr] = b0.w;
        Bsl[lc + 0][lr + 32] = b1.x; Bsl[lc + 1][lr + 32] = b1.y; Bsl[lc + 2][lr + 32] = b1.z; Bsl[lc + 3][lr + 32] = b1.w;
        __syncthreads();
        #pragma unroll
        for (int kd = 0; kd < BK; ++kd) {
            float4 av = *(const float4*)&Asl[kd][ty * 4];
            float4 bv = *(const float4*)&Bsl[kd][tx * 4];
            float a[4] = {av.x, av.y, av.z, av.w};
            float b[4] = {bv.x, bv.y, bv.z, bv.w};
            #pragma unroll
            for (int i = 0; i < 4; ++i)
                #pragma unroll
                for (int j = 0; j < 4; ++j)
                    acc[i][j] = fmaf(a[i], b[j], acc[i][j]);
        }
    }
    #pragma unroll
    for (int i = 0; i < 4; ++i) {
        int row = row0 + ty * 4 + i;
        float xs = xsq[row];
        float4 o;
        int col = col0 + tx * 4;
        o.x = 2.f * acc[i][0] - xs - esq[col + 0];
        o.y = 2.f * acc[i][1] - xs - esq[col + 1];
        o.z = 2.f * acc[i][2] - xs - esq[col + 2];
        o.w = 2.f * acc[i][3] - xs - esq[col + 3];
        *(float4*)(dist + (size_t)row * Kk + col) = o;
    }
}

__global__ void argmax_k(const float* __restrict__ dist,
                         float* __restrict__ ind_f, int* __restrict__ ind_i) {
    int row  = blockIdx.x * 4 + (threadIdx.x >> 6);
    int lane = threadIdx.x & 63;
    const float4* p = (const float4*)(dist + (size_t)row * Kk);
    float best = -3.4e38f;
    int bidx = 0;
    #pragma unroll
    for (int it = 0; it < Kk / 4 / 64; ++it) {
        int i = lane + it * 64;
        float4 v = p[i];
        int base = i * 4;
        if (v.x > best) { best = v.x; bidx = base + 0; }
        if (v.y > best) { best = v.y; bidx = base + 1; }
        if (v.z > best) { best = v.z; bidx = base + 2; }
        if (v.w > best) { best = v.w; bidx = base + 3; }
    }
    #pragma unroll
    for (int off = 32; off; off >>= 1) {
        float ov = __shfl_down(best, off);
        int   oi = __shfl_down(bidx, off);
        if (ov > best || (ov == best && oi < bidx)) { best = ov; bidx = oi; }
    }
    if (lane == 0) { ind_f[row] = (float)bidx; ind_i[row] = bidx; }
}

// ---------------- quantize gather + segment-sum scatter --------------------
__global__ void gather_scatter(const float* __restrict__ x,
                               const float* __restrict__ embed,
                               const int* __restrict__ ind,
                               float* __restrict__ quant,
                               float* __restrict__ esum,
                               int* __restrict__ bins) {
    int n = blockIdx.x;
    int k = ind[n];
    int t = threadIdx.x;
    size_t xb = (size_t)n * Dd;
    size_t eb = (size_t)k * Dd;
    float v0 = x[xb + t];
    float v1 = x[xb + t + 256];
    quant[xb + t]       = embed[eb + t];
    quant[xb + t + 256] = embed[eb + t + 256];
    atomicAdd(&esum[eb + t],       v0);
    atomicAdd(&esum[eb + t + 256], v1);
    if (t == 0) atomicAdd(&bins[k], 1);
}

// ---------------- EMA cluster size + laplace total -------------------------
__global__ void finalize1(const float* __restrict__ cs, const int* __restrict__ bins,
                          float* __restrict__ ncs, float* __restrict__ total_ws) {
    __shared__ float red[16];
    int t = threadIdx.x;
    float s = 0.f;
    for (int k = t; k < Kk; k += 1024) {
        float v = cs[k] * DECAY + OMD * (float)bins[k];
        ncs[k] = v;
        s += v;
    }
    #pragma unroll
    for (int off = 32; off; off >>= 1) s += __shfl_down(s, off);
    if ((t & 63) == 0) red[t >> 6] = s;
    __syncthreads();
    if (t == 0) {
        float tot = 0.f;
        #pragma unroll
        for (int i = 0; i < 16; ++i) tot += red[i];
        total_ws[0] = tot;
    }
}

// ---------------- EMA embed_avg + smoothed divide ---------------------------
__global__ void finalize2(const float* __restrict__ ea, const float* __restrict__ esum,
                          const float* __restrict__ ncs, const float* __restrict__ total_ws,
                          float* __restrict__ nea, float* __restrict__ ne) {
    int idx = blockIdx.x * 256 + threadIdx.x;
    float total = total_ws[0];
    int k = idx >> 7;
    float sm = (ncs[k] + EPS) / (total + Kk * EPS) * total;
    float inv = 1.f / sm;
    float4 a = ((const float4*)ea)[idx];
    float4 s = ((const float4*)esum)[idx];
    float4 r;
    r.x = a.x * DECAY + OMD * s.x;
    r.y = a.y * DECAY + OMD * s.y;
    r.z = a.z * DECAY + OMD * s.z;
    r.w = a.w * DECAY + OMD * s.w;
    ((float4*)nea)[idx] = r;
    float4 e;
    e.x = r.x * inv; e.y = r.y * inv; e.z = r.z * inv; e.w = r.w * inv;
    ((float4*)ne)[idx] = e;
}

extern "C" void kernel_launch(void* const* d_in, const int* in_sizes, int n_in,
                              void* d_out, int out_size, void* d_ws, size_t ws_size,
                              hipStream_t stream) {
    const float* x     = (const float*)d_in[0];
    const float* embed = (const float*)d_in[1];
    const float* cs    = (const float*)d_in[2];
    const float* ea    = (const float*)d_in[3];

    float* out     = (float*)d_out;
    float* o_quant = out;
    float* o_ind   = o_quant + (size_t)Nn * Dd;
    float* o_dist  = o_ind + Nn;
    float* o_ncs   = o_dist + (size_t)Nn * Kk;
    float* o_nea   = o_ncs + Kk;
    float* o_ne    = o_nea + (size_t)Kk * Dd;

    // ---- ws layout ----
    size_t xp_elems = (size_t)3 * Nn * Dd;       // bf16
    size_t ep_elems = (size_t)3 * Kk * Dd;
    char* w = (char*)d_ws;
    unsigned short* xp = (unsigned short*)w;                 w += xp_elems * 2;
    unsigned short* epp = (unsigned short*)w;                w += ep_elems * 2;
    float* xsq   = (float*)w;                                w += (size_t)Nn * 4;
    float* esq   = (float*)w;                                w += (size_t)Kk * 4;
    int*   ind_i = (int*)w;                                  w += (size_t)Nn * 4;
    int*   bins  = (int*)w;                                  w += (size_t)Kk * 4;
    float* esum  = (float*)w;                                w += (size_t)Kk * Dd * 4;
    unsigned long long* packed = (unsigned long long*)w;     w += (size_t)Nn * 8;
    float* total = (float*)w;                                w += 256;
    size_t need = (size_t)(w - (char*)d_ws);

    if (ws_size >= need) {
        // zero bins + esum + packed (contiguous)
        hipMemsetAsync(bins, 0, (size_t)Kk * 4 + (size_t)Kk * Dd * 4 + (size_t)Nn * 8, stream);

        rows_sq<<<Nn / 4, 256, 0, stream>>>(x, xsq, Nn);
        rows_sq<<<Kk / 4, 256, 0, stream>>>(embed, esq, Kk);

        conv_split<<<(Nn * Dd / 4 + 255) / 256, 256, 0, stream>>>(
            x, xp, xp + (size_t)Nn * Dd, xp + (size_t)2 * Nn * Dd, Nn * Dd / 4);
        conv_split<<<(Kk * Dd / 4 + 255) / 256, 256, 0, stream>>>(
            embed, epp, epp + (size_t)Kk * Dd, epp + (size_t)2 * Kk * Dd, Kk * Dd / 4);

        gemm_split256<<<(Nn / 256) * (Kk / 256), 512, 0, stream>>>(
            xp, epp, xsq, esq, o_dist, packed);

        unpack_argmax<<<Nn / 256, 256, 0, stream>>>(packed, o_ind, ind_i);
    } else {
        // fallback: fp32 path
        float* fxsq  = (float*)d_ws;
        float* fesq  = fxsq + Nn;
        int*   find  = (int*)(fesq + Kk);
        int*   fbins = find + Nn;
        float* fesum = (float*)(fbins + Kk);
        float* ftot  = fesum + (size_t)Kk * Dd;
        xsq = fxsq; esq = fesq; ind_i = find; bins = fbins; esum = fesum; total = ftot;

        hipMemsetAsync(bins, 0, (size_t)(Kk + Kk * Dd) * sizeof(float), stream);
        rows_sq<<<Nn / 4, 256, 0, stream>>>(x, xsq, Nn);
        rows_sq<<<Kk / 4, 256, 0, stream>>>(embed, esq, Kk);
        dim3 g(Nn / BM, Kk / BN);
        gemm_dist<<<g, 256, 0, stream>>>(x, embed, xsq, esq, o_dist);
        argmax_k<<<Nn / 4, 256, 0, stream>>>(o_dist, o_ind, ind_i);
    }

    gather_scatter<<<Nn, 256, 0, stream>>>(x, embed, ind_i, o_quant, esum, bins);
    finalize1<<<1, 1024, 0, stream>>>(cs, bins, o_ncs, total);
    finalize2<<<(Kk * Dd / 4) / 256, 256, 0, stream>>>(ea, esum, o_ncs, total, o_nea, o_ne);
}

// Round 5
// 571.176 us; speedup vs baseline: 1.0903x; 1.0903x over previous
//
#include <hip/hip_runtime.h>

#define DECAY 0.99f
#define OMD   0.01f
#define EPS   1e-5f

constexpr int Bb = 16, Ss = 2048, Dd = 512, Kk = 2048;
constexpr int Nn = Bb * Ss;  // 32768

typedef __attribute__((ext_vector_type(8))) short short8;
typedef __attribute__((ext_vector_type(4))) float f32x4;

__device__ __forceinline__ unsigned short f2bf(float x) {
    unsigned u = __float_as_uint(x);
    unsigned r = (u + 0x7FFFu + ((u >> 16) & 1u)) >> 16;   // RN-even
    return (unsigned short)r;
}
__device__ __forceinline__ float bf2f(unsigned short u) {
    return __uint_as_float((unsigned)u << 16);
}

__device__ __forceinline__ void gload_lds16(const void* g, void* l) {
    __builtin_amdgcn_global_load_lds(
        (const __attribute__((address_space(1))) void*)g,
        (__attribute__((address_space(3))) void*)l, 16, 0, 0);
}

#define BARRIER() do { asm volatile("" ::: "memory"); \
                       __builtin_amdgcn_s_barrier();  \
                       asm volatile("" ::: "memory"); } while (0)

// ---------------- row sum-of-squares ---------------------------------------
__global__ void rows_sq(const float* __restrict__ in, float* __restrict__ out, int nrows) {
    int row  = blockIdx.x * 4 + (threadIdx.x >> 6);
    int lane = threadIdx.x & 63;
    if (row >= nrows) return;
    const float4* p = (const float4*)(in + (size_t)row * Dd);
    float s = 0.f;
    #pragma unroll
    for (int i = 0; i < 2; ++i) {
        float4 v = p[lane + 64 * i];
        s += v.x * v.x + v.y * v.y + v.z * v.z + v.w * v.w;
    }
    #pragma unroll
    for (int off = 32; off; off >>= 1) s += __shfl_down(s, off);
    if (lane == 0) out[row] = s;
}

// ---------------- fp32 -> bf16x3 split -------------------------------------
__global__ void conv_split(const float* __restrict__ in,
                           unsigned short* __restrict__ ph,
                           unsigned short* __restrict__ pm,
                           unsigned short* __restrict__ pl, int n4) {
    int i = blockIdx.x * 256 + threadIdx.x;
    if (i >= n4) return;
    float4 v = ((const float4*)in)[i];
    float f[4] = {v.x, v.y, v.z, v.w};
    ushort4 h, m, l;
    unsigned short hh[4], mm[4], ll[4];
    #pragma unroll
    for (int j = 0; j < 4; ++j) {
        float x = f[j];
        unsigned short a = f2bf(x);  float ra = x - bf2f(a);
        unsigned short b = f2bf(ra); float rb = ra - bf2f(b);
        unsigned short c = f2bf(rb);
        hh[j] = a; mm[j] = b; ll[j] = c;
    }
    h.x = hh[0]; h.y = hh[1]; h.z = hh[2]; h.w = hh[3];
    m.x = mm[0]; m.y = mm[1]; m.z = mm[2]; m.w = mm[3];
    l.x = ll[0]; l.y = ll[1]; l.z = ll[2]; l.w = ll[3];
    ((ushort4*)ph)[i] = h;
    ((ushort4*)pm)[i] = m;
    ((ushort4*)pl)[i] = l;
}

// ---------------- bf16x3 MFMA GEMM, 256x256 tile, 4-phase, 1 barrier/phase -
__global__ __launch_bounds__(512, 1) void gemm_split256(
    const unsigned short* __restrict__ xp,   // [3][Nn][512] bf16 planes
    const unsigned short* __restrict__ ep,   // [3][Kk][512]
    const float* __restrict__ xsq,
    const float* __restrict__ esq,
    float* __restrict__ dist,                // [Nn, Kk]
    unsigned long long* __restrict__ packed) // [Nn] argmax accumulator
{
    __shared__ unsigned short As[2][256][64];   // 64 KB
    __shared__ unsigned short Bs[2][256][64];   // 64 KB

    const int tid  = threadIdx.x;
    const int lane = tid & 63;
    const int wid  = tid >> 6;
    const int wr   = wid >> 2;   // 0..1  (M, 128 rows each)
    const int wc   = wid & 3;    // 0..3  (N, 64 cols each)

    // XCD-aware swizzle (nwg = 1024, divisible by 8 -> bijective)
    int bid = blockIdx.x;
    int wg  = (bid & 7) * 128 + (bid >> 3);
    int mb  = wg >> 3, nb = wg & 7;
    const int row0 = mb * 256, col0 = nb * 256;

    f32x4 acc[8][4] = {};
    short8 af[4], afh[4], bf[2], bfh[2];

    const int l8   = lane >> 3;          // 0..7
    const int csrc = (lane & 7) ^ l8;    // pre-swizzled source chunk

    auto stageAt = [&](const unsigned short* pl, int d, int tt) {
        int ko = (tt & 7) * 64;
        #pragma unroll
        for (int jj = 0; jj < 4; ++jj) {
            int rowbase = jj * 64 + wid * 8;
            const unsigned short* src =
                pl + (size_t)(row0 + rowbase + l8) * Dd + ko + csrc * 8;
            gload_lds16(src, &As[d][rowbase][0]);
        }
    };
    auto stageBt = [&](const unsigned short* pl, int d, int tt) {
        int ko = (tt & 7) * 64;
        #pragma unroll
        for (int jj = 0; jj < 4; ++jj) {
            int rowbase = jj * 64 + wid * 8;
            const unsigned short* src =
                pl + (size_t)(col0 + rowbase + l8) * Dd + ko + csrc * 8;
            gload_lds16(src, &Bs[d][rowbase][0]);
        }
    };

    auto readA4 = [&](int d, int msel) {
        #pragma unroll
        for (int m = 0; m < 4; ++m) {
            int r  = wr * 128 + (msel * 4 + m) * 16 + (lane & 15);
            int c  = ((lane >> 4))     ^ (r & 7);
            int c2 = ((lane >> 4) + 4) ^ (r & 7);
            af[m]  = *(const short8*)&As[d][r][c * 8];
            afh[m] = *(const short8*)&As[d][r][c2 * 8];
        }
    };
    auto readB2 = [&](int d, int nsel) {
        #pragma unroll
        for (int n = 0; n < 2; ++n) {
            int r  = wc * 64 + (nsel * 2 + n) * 16 + (lane & 15);
            int c  = ((lane >> 4))     ^ (r & 7);
            int c2 = ((lane >> 4) + 4) ^ (r & 7);
            bf[n]  = *(const short8*)&Bs[d][r][c * 8];
            bfh[n] = *(const short8*)&Bs[d][r][c2 * 8];
        }
    };

    auto mfmaQ = [&](int msel, int nsel) {
        __builtin_amdgcn_s_setprio(1);
        #pragma unroll
        for (int m = 0; m < 4; ++m)
            #pragma unroll
            for (int n = 0; n < 2; ++n) {
                int am = msel * 4 + m, bn = nsel * 2 + n;
                acc[am][bn] = __builtin_amdgcn_mfma_f32_16x16x32_bf16(af[m], bf[n], acc[am][bn], 0, 0, 0);
            }
        #pragma unroll
        for (int m = 0; m < 4; ++m)
            #pragma unroll
            for (int n = 0; n < 2; ++n) {
                int am = msel * 4 + m, bn = nsel * 2 + n;
                acc[am][bn] = __builtin_amdgcn_mfma_f32_16x16x32_bf16(afh[m], bfh[n], acc[am][bn], 0, 0, 0);
            }
        __builtin_amdgcn_s_setprio(0);
    };

    // prologue: stage tile 0 into slot 0
    stageAt(xp, 0, 0);
    stageBt(ep, 0, 0);
    asm volatile("s_waitcnt vmcnt(0)" ::: "memory");
    BARRIER();

    for (int t = 0; t < 48; ++t) {
        const int cur = t & 1, nxt = cur ^ 1;
        const bool st = (t < 47);
        // plane pointers for tile t+1 (ternaries, no local arrays)
        int pn = (t + 1) >> 3;
        const unsigned short* Apn = xp + (size_t)((pn == 2 || pn == 3) ? 1 : (pn == 5) ? 2 : 0) * ((size_t)Nn * Dd);
        const unsigned short* Bpn = ep + (size_t)((pn == 1 || pn == 3) ? 1 : (pn == 4) ? 2 : 0) * ((size_t)Kk * Dd);

        // ---- ph0 ----
        readA4(cur, 0); readB2(cur, 0);
        if (st) { stageAt(Apn, nxt, t + 1); stageBt(Bpn, nxt, t + 1); }
        mfmaQ(0, 0);
        BARRIER();
        // ---- ph1 ----
        readB2(cur, 1);
        mfmaQ(0, 1);
        BARRIER();
        // ---- ph2 ----
        readA4(cur, 1);
        mfmaQ(1, 1);
        BARRIER();
        // ---- ph3 ----
        readB2(cur, 0);
        mfmaQ(1, 0);
        asm volatile("s_waitcnt vmcnt(0)" ::: "memory");
        BARRIER();
    }

    // epilogue: dist = 2*dot - xsq - esq ; fused per-row argmax
    const int jrow = (lane >> 4) * 4;
    const int ncol = lane & 15;
    #pragma unroll
    for (int m = 0; m < 8; ++m) {
        int rbase = row0 + wr * 128 + m * 16 + jrow;
        #pragma unroll
        for (int j = 0; j < 4; ++j) {
            int row = rbase + j;
            float xs = xsq[row];
            float best = -3.4e38f; int bi = 0;
            #pragma unroll
            for (int n = 0; n < 4; ++n) {
                int col = col0 + wc * 64 + n * 16 + ncol;
                float v = 2.f * acc[m][n][j] - xs - esq[col];
                dist[(size_t)row * Kk + col] = v;
                if (v > best) { best = v; bi = col; }
            }
            unsigned u = __float_as_uint(best);
            u = (u & 0x80000000u) ? ~u : (u | 0x80000000u);
            unsigned long long pk = ((unsigned long long)u << 32) | (unsigned)(~bi);
            #pragma unroll
            for (int off = 1; off < 16; off <<= 1) {
                unsigned long long o = __shfl_xor(pk, off);
                if (o > pk) pk = o;
            }
            if (ncol == 0) atomicMax(&packed[row], pk);
        }
    }
}

__global__ void unpack_argmax(const unsigned long long* __restrict__ packed,
                              float* __restrict__ ind_f, int* __restrict__ ind_i) {
    int i = blockIdx.x * 256 + threadIdx.x;
    unsigned long long p = packed[i];
    int k = (int)(~(unsigned)(p & 0xFFFFFFFFull));
    ind_f[i] = (float)k;
    ind_i[i] = k;
}

// ---------------- OLD fp32 GEMM (fallback when ws too small) ---------------
#define BM 64
#define BN 64
#define BK 32
__global__ __launch_bounds__(256) void gemm_dist(
    const float* __restrict__ A, const float* __restrict__ Bm,
    const float* __restrict__ xsq, const float* __restrict__ esq,
    float* __restrict__ dist)
{
    __shared__ float Asl[BK][BM + 4];
    __shared__ float Bsl[BK][BN + 4];
    int tid = threadIdx.x;
    int row0 = blockIdx.x * BM, col0 = blockIdx.y * BN;
    int tx = tid & 15, ty = tid >> 4;
    float acc[4][4] = {};
    int lr = tid >> 3, lc = (tid & 7) * 4;
    for (int d0 = 0; d0 < Dd; d0 += BK) {
        float4 a0 = *(const float4*)(A  + (size_t)(row0 + lr)      * Dd + d0 + lc);
        float4 a1 = *(const float4*)(A  + (size_t)(row0 + lr + 32) * Dd + d0 + lc);
        float4 b0 = *(const float4*)(Bm + (size_t)(col0 + lr)      * Dd + d0 + lc);
        float4 b1 = *(const float4*)(Bm + (size_t)(col0 + lr + 32) * Dd + d0 + lc);
        __syncthreads();
        Asl[lc + 0][lr] = a0.x; Asl[lc + 1][lr] = a0.y; Asl[lc + 2][lr] = a0.z; Asl[lc + 3][lr] = a0.w;
        Asl[lc + 0][lr + 32] = a1.x; Asl[lc + 1][lr + 32] = a1.y; Asl[lc + 2][lr + 32] = a1.z; Asl[lc + 3][lr + 32] = a1.w;
        Bsl[lc + 0][lr] = b0.x; Bsl[lc + 1][lr] = b0.y; Bsl[lc + 2][lr] = b0.z; Bsl[lc + 3][lr] = b0.w;
        Bsl[lc + 0][lr + 32] = b1.x; Bsl[lc + 1][lr + 32] = b1.y; Bsl[lc + 2][lr + 32] = b1.z; Bsl[lc + 3][lr + 32] = b1.w;
        __syncthreads();
        #pragma unroll
        for (int kd = 0; kd < BK; ++kd) {
            float4 av = *(const float4*)&Asl[kd][ty * 4];
            float4 bv = *(const float4*)&Bsl[kd][tx * 4];
            float a[4] = {av.x, av.y, av.z, av.w};
            float b[4] = {bv.x, bv.y, bv.z, bv.w};
            #pragma unroll
            for (int i = 0; i < 4; ++i)
                #pragma unroll
                for (int j = 0; j < 4; ++j)
                    acc[i][j] = fmaf(a[i], b[j], acc[i][j]);
        }
    }
    #pragma unroll
    for (int i = 0; i < 4; ++i) {
        int row = row0 + ty * 4 + i;
        float xs = xsq[row];
        float4 o;
        int col = col0 + tx * 4;
        o.x = 2.f * acc[i][0] - xs - esq[col + 0];
        o.y = 2.f * acc[i][1] - xs - esq[col + 1];
        o.z = 2.f * acc[i][2] - xs - esq[col + 2];
        o.w = 2.f * acc[i][3] - xs - esq[col + 3];
        *(float4*)(dist + (size_t)row * Kk + col) = o;
    }
}

__global__ void argmax_k(const float* __restrict__ dist,
                         float* __restrict__ ind_f, int* __restrict__ ind_i) {
    int row  = blockIdx.x * 4 + (threadIdx.x >> 6);
    int lane = threadIdx.x & 63;
    const float4* p = (const float4*)(dist + (size_t)row * Kk);
    float best = -3.4e38f;
    int bidx = 0;
    #pragma unroll
    for (int it = 0; it < Kk / 4 / 64; ++it) {
        int i = lane + it * 64;
        float4 v = p[i];
        int base = i * 4;
        if (v.x > best) { best = v.x; bidx = base + 0; }
        if (v.y > best) { best = v.y; bidx = base + 1; }
        if (v.z > best) { best = v.z; bidx = base + 2; }
        if (v.w > best) { best = v.w; bidx = base + 3; }
    }
    #pragma unroll
    for (int off = 32; off; off >>= 1) {
        float ov = __shfl_down(best, off);
        int   oi = __shfl_down(bidx, off);
        if (ov > best || (ov == best && oi < bidx)) { best = ov; bidx = oi; }
    }
    if (lane == 0) { ind_f[row] = (float)bidx; ind_i[row] = bidx; }
}

// ---------------- quantize gather + segment-sum scatter --------------------
__global__ void gather_scatter(const float* __restrict__ x,
                               const float* __restrict__ embed,
                               const int* __restrict__ ind,
                               float* __restrict__ quant,
                               float* __restrict__ esum,
                               int* __restrict__ bins) {
    int n = blockIdx.x;
    int k = ind[n];
    int t = threadIdx.x;
    size_t xb = (size_t)n * Dd;
    size_t eb = (size_t)k * Dd;
    float v0 = x[xb + t];
    float v1 = x[xb + t + 256];
    quant[xb + t]       = embed[eb + t];
    quant[xb + t + 256] = embed[eb + t + 256];
    atomicAdd(&esum[eb + t],       v0);
    atomicAdd(&esum[eb + t + 256], v1);
    if (t == 0) atomicAdd(&bins[k], 1);
}

// ---------------- EMA cluster size + laplace total -------------------------
__global__ void finalize1(const float* __restrict__ cs, const int* __restrict__ bins,
                          float* __restrict__ ncs, float* __restrict__ total_ws) {
    __shared__ float red[16];
    int t = threadIdx.x;
    float s = 0.f;
    for (int k = t; k < Kk; k += 1024) {
        float v = cs[k] * DECAY + OMD * (float)bins[k];
        ncs[k] = v;
        s += v;
    }
    #pragma unroll
    for (int off = 32; off; off >>= 1) s += __shfl_down(s, off);
    if ((t & 63) == 0) red[t >> 6] = s;
    __syncthreads();
    if (t == 0) {
        float tot = 0.f;
        #pragma unroll
        for (int i = 0; i < 16; ++i) tot += red[i];
        total_ws[0] = tot;
    }
}

// ---------------- EMA embed_avg + smoothed divide ---------------------------
__global__ void finalize2(const float* __restrict__ ea, const float* __restrict__ esum,
                          const float* __restrict__ ncs, const float* __restrict__ total_ws,
                          float* __restrict__ nea, float* __restrict__ ne) {
    int idx = blockIdx.x * 256 + threadIdx.x;
    float total = total_ws[0];
    int k = idx >> 7;
    float sm = (ncs[k] + EPS) / (total + Kk * EPS) * total;
    float inv = 1.f / sm;
    float4 a = ((const float4*)ea)[idx];
    float4 s = ((const float4*)esum)[idx];
    float4 r;
    r.x = a.x * DECAY + OMD * s.x;
    r.y = a.y * DECAY + OMD * s.y;
    r.z = a.z * DECAY + OMD * s.z;
    r.w = a.w * DECAY + OMD * s.w;
    ((float4*)nea)[idx] = r;
    float4 e;
    e.x = r.x * inv; e.y = r.y * inv; e.z = r.z * inv; e.w = r.w * inv;
    ((float4*)ne)[idx] = e;
}

extern "C" void kernel_launch(void* const* d_in, const int* in_sizes, int n_in,
                              void* d_out, int out_size, void* d_ws, size_t ws_size,
                              hipStream_t stream) {
    const float* x     = (const float*)d_in[0];
    const float* embed = (const float*)d_in[1];
    const float* cs    = (const float*)d_in[2];
    const float* ea    = (const float*)d_in[3];

    float* out     = (float*)d_out;
    float* o_quant = out;
    float* o_ind   = o_quant + (size_t)Nn * Dd;
    float* o_dist  = o_ind + Nn;
    float* o_ncs   = o_dist + (size_t)Nn * Kk;
    float* o_nea   = o_ncs + Kk;
    float* o_ne    = o_nea + (size_t)Kk * Dd;

    // ---- ws layout ----
    size_t xp_elems = (size_t)3 * Nn * Dd;       // bf16
    size_t ep_elems = (size_t)3 * Kk * Dd;
    char* w = (char*)d_ws;
    unsigned short* xp = (unsigned short*)w;                 w += xp_elems * 2;
    unsigned short* epp = (unsigned short*)w;                w += ep_elems * 2;
    float* xsq   = (float*)w;                                w += (size_t)Nn * 4;
    float* esq   = (float*)w;                                w += (size_t)Kk * 4;
    int*   ind_i = (int*)w;                                  w += (size_t)Nn * 4;
    int*   bins  = (int*)w;                                  w += (size_t)Kk * 4;
    float* esum  = (float*)w;                                w += (size_t)Kk * Dd * 4;
    unsigned long long* packed = (unsigned long long*)w;     w += (size_t)Nn * 8;
    float* total = (float*)w;                                w += 256;
    size_t need = (size_t)(w - (char*)d_ws);

    if (ws_size >= need) {
        hipMemsetAsync(bins, 0, (size_t)Kk * 4 + (size_t)Kk * Dd * 4 + (size_t)Nn * 8, stream);

        rows_sq<<<Nn / 4, 256, 0, stream>>>(x, xsq, Nn);
        rows_sq<<<Kk / 4, 256, 0, stream>>>(embed, esq, Kk);

        conv_split<<<(Nn * Dd / 4 + 255) / 256, 256, 0, stream>>>(
            x, xp, xp + (size_t)Nn * Dd, xp + (size_t)2 * Nn * Dd, Nn * Dd / 4);
        conv_split<<<(Kk * Dd / 4 + 255) / 256, 256, 0, stream>>>(
            embed, epp, epp + (size_t)Kk * Dd, epp + (size_t)2 * Kk * Dd, Kk * Dd / 4);

        gemm_split256<<<(Nn / 256) * (Kk / 256), 512, 0, stream>>>(
            xp, epp, xsq, esq, o_dist, packed);

        unpack_argmax<<<Nn / 256, 256, 0, stream>>>(packed, o_ind, ind_i);
    } else {
        float* fxsq  = (float*)d_ws;
        float* fesq  = fxsq + Nn;
        int*   find  = (int*)(fesq + Kk);
        int*   fbins = find + Nn;
        float* fesum = (float*)(fbins + Kk);
        float* ftot  = fesum + (size_t)Kk * Dd;
        xsq = fxsq; esq = fesq; ind_i = find; bins = fbins; esum = fesum; total = ftot;

        hipMemsetAsync(bins, 0, (size_t)(Kk + Kk * Dd) * sizeof(float), stream);
        rows_sq<<<Nn / 4, 256, 0, stream>>>(x, xsq, Nn);
        rows_sq<<<Kk / 4, 256, 0, stream>>>(embed, esq, Kk);
        dim3 g(Nn / BM, Kk / BN);
        gemm_dist<<<g, 256, 0, stream>>>(x, embed, xsq, esq, o_dist);
        argmax_k<<<Nn / 4, 256, 0, stream>>>(o_dist, o_ind, ind_i);
    }

    gather_scatter<<<Nn, 256, 0, stream>>>(x, embed, ind_i, o_quant, esum, bins);
    finalize1<<<1, 1024, 0, stream>>>(cs, bins, o_ncs, total);
    finalize2<<<(Kk * Dd / 4) / 256, 256, 0, stream>>>(ea, esum, o_ncs, total, o_nea, o_ne);
}

// Round 6
// 568.356 us; speedup vs baseline: 1.0957x; 1.0050x over previous
//
#include <hip/hip_runtime.h>

#define DECAY 0.99f
#define OMD   0.01f
#define EPS   1e-5f

constexpr int Bb = 16, Ss = 2048, Dd = 512, Kk = 2048;
constexpr int Nn = Bb * Ss;  // 32768

typedef __attribute__((ext_vector_type(8))) short short8;
typedef __attribute__((ext_vector_type(4))) float f32x4;

__device__ __forceinline__ unsigned short f2bf(float x) {
    unsigned u = __float_as_uint(x);
    unsigned r = (u + 0x7FFFu + ((u >> 16) & 1u)) >> 16;   // RN-even
    return (unsigned short)r;
}
__device__ __forceinline__ float bf2f(unsigned short u) {
    return __uint_as_float((unsigned)u << 16);
}

__device__ __forceinline__ void gload_lds16(const void* g, void* l) {
    __builtin_amdgcn_global_load_lds(
        (const __attribute__((address_space(1))) void*)g,
        (__attribute__((address_space(3))) void*)l, 16, 0, 0);
}

#define BARRIER() do { asm volatile("" ::: "memory"); \
                       __builtin_amdgcn_s_barrier();  \
                       asm volatile("" ::: "memory"); } while (0)

// ---------------- row sum-of-squares ---------------------------------------
__global__ void rows_sq(const float* __restrict__ in, float* __restrict__ out, int nrows) {
    int row  = blockIdx.x * 4 + (threadIdx.x >> 6);
    int lane = threadIdx.x & 63;
    if (row >= nrows) return;
    const float4* p = (const float4*)(in + (size_t)row * Dd);
    float s = 0.f;
    #pragma unroll
    for (int i = 0; i < 2; ++i) {
        float4 v = p[lane + 64 * i];
        s += v.x * v.x + v.y * v.y + v.z * v.z + v.w * v.w;
    }
    #pragma unroll
    for (int off = 32; off; off >>= 1) s += __shfl_down(s, off);
    if (lane == 0) out[row] = s;
}

// ---------------- fp32 -> bf16x3 split -------------------------------------
__global__ void conv_split(const float* __restrict__ in,
                           unsigned short* __restrict__ ph,
                           unsigned short* __restrict__ pm,
                           unsigned short* __restrict__ pl, int n4) {
    int i = blockIdx.x * 256 + threadIdx.x;
    if (i >= n4) return;
    float4 v = ((const float4*)in)[i];
    float f[4] = {v.x, v.y, v.z, v.w};
    ushort4 h, m, l;
    unsigned short hh[4], mm[4], ll[4];
    #pragma unroll
    for (int j = 0; j < 4; ++j) {
        float x = f[j];
        unsigned short a = f2bf(x);  float ra = x - bf2f(a);
        unsigned short b = f2bf(ra); float rb = ra - bf2f(b);
        unsigned short c = f2bf(rb);
        hh[j] = a; mm[j] = b; ll[j] = c;
    }
    h.x = hh[0]; h.y = hh[1]; h.z = hh[2]; h.w = hh[3];
    m.x = mm[0]; m.y = mm[1]; m.z = mm[2]; m.w = mm[3];
    l.x = ll[0]; l.y = ll[1]; l.z = ll[2]; l.w = ll[3];
    ((ushort4*)ph)[i] = h;
    ((ushort4*)pm)[i] = m;
    ((ushort4*)pl)[i] = l;
}

// ---------------- bf16x3 MFMA GEMM, 256x256 tile, m201-style 8-phase -------
// K_eff = 6*512 = 3072 -> 48 K-tiles of BK=64, 24 iters x 2 tiles.
// buf0 = even tile, buf1 = odd tile. Reads of a tile finish by its 3rd phase;
// stages (4 gloads each) at ph0/ph3/ph4/ph7 target dead slots only.
// Counted vmcnt(4) at ph3/ph7; B-lo held in regs (24 ds_read/wave/K-tile).
__global__ __launch_bounds__(512, 1) void gemm_split256(
    const unsigned short* __restrict__ xp,   // [3][Nn][512] bf16 planes
    const unsigned short* __restrict__ ep,   // [3][Kk][512]
    const float* __restrict__ xsq,
    const float* __restrict__ esq,
    float* __restrict__ dist,                // [Nn, Kk]
    unsigned long long* __restrict__ packed) // [Nn] argmax accumulator
{
    __shared__ unsigned short As[2][256][64];   // 64 KB
    __shared__ unsigned short Bs[2][256][64];   // 64 KB

    const int tid  = threadIdx.x;
    const int lane = tid & 63;
    const int wid  = tid >> 6;
    const int wr   = wid >> 2;   // 0..1  (M, 128 rows each)
    const int wc   = wid & 3;    // 0..3  (N, 64 cols each)

    // XCD-aware swizzle (nwg = 1024, divisible by 8 -> bijective)
    int bid = blockIdx.x;
    int wg  = (bid & 7) * 128 + (bid >> 3);
    int mb  = wg >> 3, nb = wg & 7;
    const int row0 = mb * 256, col0 = nb * 256;

    f32x4 acc[8][4] = {};
    short8 af[4], afh[4], bl[2], blh[2], bh[2], bhh[2];

    const int l8   = lane >> 3;          // 0..7
    const int csrc = (lane & 7) ^ l8;    // pre-swizzled source chunk

    // plane selection (ternaries -> s_cselect, no LUT/scratch)
    auto Aplane = [&](int tt) -> const unsigned short* {
        int p = tt >> 3;   // A parts: h,h,m,m,h,l
        size_t off = (p == 2 || p == 3) ? 1 : (p == 5) ? 2 : 0;
        return xp + off * ((size_t)Nn * Dd);
    };
    auto Bplane = [&](int tt) -> const unsigned short* {
        int p = tt >> 3;   // B parts: h,m,h,m,l,h
        size_t off = (p == 1 || p == 3) ? 1 : (p == 4) ? 2 : 0;
        return ep + off * ((size_t)Kk * Dd);
    };

    // stage one 128-row half (2 gloads/thread = 16 KB)
    auto stageA = [&](int d, int half, const unsigned short* pl, int ko) {
        #pragma unroll
        for (int jj = 0; jj < 2; ++jj) {
            int rowbase = half * 128 + jj * 64 + wid * 8;
            const unsigned short* src =
                pl + (size_t)(row0 + rowbase + l8) * Dd + ko + csrc * 8;
            gload_lds16(src, &As[d][rowbase][0]);
        }
    };
    auto stageB = [&](int d, int half, const unsigned short* pl, int ko) {
        #pragma unroll
        for (int jj = 0; jj < 2; ++jj) {
            int rowbase = half * 128 + jj * 64 + wid * 8;
            const unsigned short* src =
                pl + (size_t)(col0 + rowbase + l8) * Dd + ko + csrc * 8;
            gload_lds16(src, &Bs[d][rowbase][0]);
        }
    };

    auto readA = [&](int d, int msel) {
        #pragma unroll
        for (int m = 0; m < 4; ++m) {
            int r  = wr * 128 + (msel * 4 + m) * 16 + (lane & 15);
            int c  = ((lane >> 4))     ^ (r & 7);
            int c2 = ((lane >> 4) + 4) ^ (r & 7);
            af[m]  = *(const short8*)&As[d][r][c * 8];
            afh[m] = *(const short8*)&As[d][r][c2 * 8];
        }
    };
    auto readBlo = [&](int d) {
        #pragma unroll
        for (int n = 0; n < 2; ++n) {
            int r  = wc * 64 + n * 16 + (lane & 15);
            int c  = ((lane >> 4))     ^ (r & 7);
            int c2 = ((lane >> 4) + 4) ^ (r & 7);
            bl[n]  = *(const short8*)&Bs[d][r][c * 8];
            blh[n] = *(const short8*)&Bs[d][r][c2 * 8];
        }
    };
    auto readBhi = [&](int d) {
        #pragma unroll
        for (int n = 0; n < 2; ++n) {
            int r  = wc * 64 + (2 + n) * 16 + (lane & 15);
            int c  = ((lane >> 4))     ^ (r & 7);
            int c2 = ((lane >> 4) + 4) ^ (r & 7);
            bh[n]  = *(const short8*)&Bs[d][r][c * 8];
            bhh[n] = *(const short8*)&Bs[d][r][c2 * 8];
        }
    };

    auto mfmaQ = [&](int msel, int nsel, const short8* b0, const short8* b1) {
        __builtin_amdgcn_s_setprio(1);
        #pragma unroll
        for (int m = 0; m < 4; ++m)
            #pragma unroll
            for (int n = 0; n < 2; ++n) {
                int am = msel * 4 + m, bn = nsel * 2 + n;
                acc[am][bn] = __builtin_amdgcn_mfma_f32_16x16x32_bf16(af[m], b0[n], acc[am][bn], 0, 0, 0);
            }
        #pragma unroll
        for (int m = 0; m < 4; ++m)
            #pragma unroll
            for (int n = 0; n < 2; ++n) {
                int am = msel * 4 + m, bn = nsel * 2 + n;
                acc[am][bn] = __builtin_amdgcn_mfma_f32_16x16x32_bf16(afh[m], b1[n], acc[am][bn], 0, 0, 0);
            }
        __builtin_amdgcn_s_setprio(0);
    };

    // prologue: tile0 fully (8 loads) + tile1 A halves (4 loads); vmcnt(4)
    stageA(0, 0, Aplane(0), 0); stageA(0, 1, Aplane(0), 0);
    stageB(0, 0, Bplane(0), 0); stageB(0, 1, Bplane(0), 0);
    stageA(1, 0, Aplane(1), 64); stageA(1, 1, Aplane(1), 64);
    asm volatile("s_waitcnt vmcnt(4)" ::: "memory");
    BARRIER();

    for (int i = 0; i < 24; ++i) {
        const int t = 2 * i;
        const bool s2 = (t + 2) < 48, s3 = (t + 3) < 48;
        const unsigned short* Bp1 = Bplane(t + 1);
        const unsigned short* Ap2 = Aplane(t + 2);
        const unsigned short* Bp2 = Bplane(t + 2);
        const unsigned short* Ap3 = Aplane(t + 3);
        const int ko1 = ((t + 1) & 7) * 64;
        const int ko2 = ((t + 2) & 7) * 64;
        const int ko3 = ((t + 3) & 7) * 64;

        // ---- ph0: reads A(lo-half of wave),B-lo of tile t; stage buf1.B(t+1)
        readA(0, 0); readBlo(0);
        stageB(1, 0, Bp1, ko1); stageB(1, 1, Bp1, ko1);
        BARRIER(); mfmaQ(0, 0, bl, blh); BARRIER();
        // ---- ph1: read B-hi ----
        readBhi(0);
        BARRIER(); mfmaQ(0, 1, bh, bhh); BARRIER();
        // ---- ph2: read A msel1 ----
        readA(0, 1);
        BARRIER(); mfmaQ(1, 1, bh, bhh); BARRIER();
        // ---- ph3: no reads (B-lo held); stage buf0.A(t+2); vmcnt(4) ----
        if (s2) { stageA(0, 0, Ap2, ko2); stageA(0, 1, Ap2, ko2); }
        BARRIER(); mfmaQ(1, 0, bl, blh);
        if (s2) { asm volatile("s_waitcnt vmcnt(4)" ::: "memory"); }
        else    { asm volatile("s_waitcnt vmcnt(0)" ::: "memory"); }
        BARRIER();
        // ---- ph4: tile t+1 from buf1; stage buf0.B(t+2) ----
        readA(1, 0); readBlo(1);
        if (s2) { stageB(0, 0, Bp2, ko2); stageB(0, 1, Bp2, ko2); }
        BARRIER(); mfmaQ(0, 0, bl, blh); BARRIER();
        // ---- ph5 ----
        readBhi(1);
        BARRIER(); mfmaQ(0, 1, bh, bhh); BARRIER();
        // ---- ph6 ----
        readA(1, 1);
        BARRIER(); mfmaQ(1, 1, bh, bhh); BARRIER();
        // ---- ph7: stage buf1.A(t+3); vmcnt(4) ----
        if (s3) { stageA(1, 0, Ap3, ko3); stageA(1, 1, Ap3, ko3); }
        BARRIER(); mfmaQ(1, 0, bl, blh);
        if (s3) { asm volatile("s_waitcnt vmcnt(4)" ::: "memory"); }
        else    { asm volatile("s_waitcnt vmcnt(0)" ::: "memory"); }
        BARRIER();
    }
    asm volatile("s_waitcnt vmcnt(0)" ::: "memory");

    // epilogue: dist = 2*dot - xsq - esq ; fused per-row argmax
    const int jrow = (lane >> 4) * 4;
    const int ncol = lane & 15;
    #pragma unroll
    for (int m = 0; m < 8; ++m) {
        int rbase = row0 + wr * 128 + m * 16 + jrow;
        #pragma unroll
        for (int j = 0; j < 4; ++j) {
            int row = rbase + j;
            float xs = xsq[row];
            float best = -3.4e38f; int bi = 0;
            #pragma unroll
            for (int n = 0; n < 4; ++n) {
                int col = col0 + wc * 64 + n * 16 + ncol;
                float v = 2.f * acc[m][n][j] - xs - esq[col];
                dist[(size_t)row * Kk + col] = v;
                if (v > best) { best = v; bi = col; }
            }
            unsigned u = __float_as_uint(best);
            u = (u & 0x80000000u) ? ~u : (u | 0x80000000u);
            unsigned long long pk = ((unsigned long long)u << 32) | (unsigned)(~bi);
            #pragma unroll
            for (int off = 1; off < 16; off <<= 1) {
                unsigned long long o = __shfl_xor(pk, off);
                if (o > pk) pk = o;
            }
            if (ncol == 0) atomicMax(&packed[row], pk);
        }
    }
}

__global__ void unpack_argmax(const unsigned long long* __restrict__ packed,
                              float* __restrict__ ind_f, int* __restrict__ ind_i) {
    int i = blockIdx.x * 256 + threadIdx.x;
    unsigned long long p = packed[i];
    int k = (int)(~(unsigned)(p & 0xFFFFFFFFull));
    ind_f[i] = (float)k;
    ind_i[i] = k;
}

// ---------------- OLD fp32 GEMM (fallback when ws too small) ---------------
#define BM 64
#define BN 64
#define BK 32
__global__ __launch_bounds__(256) void gemm_dist(
    const float* __restrict__ A, const float* __restrict__ Bm,
    const float* __restrict__ xsq, const float* __restrict__ esq,
    float* __restrict__ dist)
{
    __shared__ float Asl[BK][BM + 4];
    __shared__ float Bsl[BK][BN + 4];
    int tid = threadIdx.x;
    int row0 = blockIdx.x * BM, col0 = blockIdx.y * BN;
    int tx = tid & 15, ty = tid >> 4;
    float acc[4][4] = {};
    int lr = tid >> 3, lc = (tid & 7) * 4;
    for (int d0 = 0; d0 < Dd; d0 += BK) {
        float4 a0 = *(const float4*)(A  + (size_t)(row0 + lr)      * Dd + d0 + lc);
        float4 a1 = *(const float4*)(A  + (size_t)(row0 + lr + 32) * Dd + d0 + lc);
        float4 b0 = *(const float4*)(Bm + (size_t)(col0 + lr)      * Dd + d0 + lc);
        float4 b1 = *(const float4*)(Bm + (size_t)(col0 + lr + 32) * Dd + d0 + lc);
        __syncthreads();
        Asl[lc + 0][lr] = a0.x; Asl[lc + 1][lr] = a0.y; Asl[lc + 2][lr] = a0.z; Asl[lc + 3][lr] = a0.w;
        Asl[lc + 0][lr + 32] = a1.x; Asl[lc + 1][lr + 32] = a1.y; Asl[lc + 2][lr + 32] = a1.z; Asl[lc + 3][lr + 32] = a1.w;
        Bsl[lc + 0][lr] = b0.x; Bsl[lc + 1][lr] = b0.y; Bsl[lc + 2][lr] = b0.z; Bsl[lc + 3][lr] = b0.w;
        Bsl[lc + 0][lr + 32] = b1.x; Bsl[lc + 1][lr + 32] = b1.y; Bsl[lc + 2][lr + 32] = b1.z; Bsl[lc + 3][lr + 32] = b1.w;
        __syncthreads();
        #pragma unroll
        for (int kd = 0; kd < BK; ++kd) {
            float4 av = *(const float4*)&Asl[kd][ty * 4];
            float4 bv = *(const float4*)&Bsl[kd][tx * 4];
            float a[4] = {av.x, av.y, av.z, av.w};
            float b[4] = {bv.x, bv.y, bv.z, bv.w};
            #pragma unroll
            for (int i = 0; i < 4; ++i)
                #pragma unroll
                for (int j = 0; j < 4; ++j)
                    acc[i][j] = fmaf(a[i], b[j], acc[i][j]);
        }
    }
    #pragma unroll
    for (int i = 0; i < 4; ++i) {
        int row = row0 + ty * 4 + i;
        float xs = xsq[row];
        float4 o;
        int col = col0 + tx * 4;
        o.x = 2.f * acc[i][0] - xs - esq[col + 0];
        o.y = 2.f * acc[i][1] - xs - esq[col + 1];
        o.z = 2.f * acc[i][2] - xs - esq[col + 2];
        o.w = 2.f * acc[i][3] - xs - esq[col + 3];
        *(float4*)(dist + (size_t)row * Kk + col) = o;
    }
}

__global__ void argmax_k(const float* __restrict__ dist,
                         float* __restrict__ ind_f, int* __restrict__ ind_i) {
    int row  = blockIdx.x * 4 + (threadIdx.x >> 6);
    int lane = threadIdx.x & 63;
    const float4* p = (const float4*)(dist + (size_t)row * Kk);
    float best = -3.4e38f;
    int bidx = 0;
    #pragma unroll
    for (int it = 0; it < Kk / 4 / 64; ++it) {
        int i = lane + it * 64;
        float4 v = p[i];
        int base = i * 4;
        if (v.x > best) { best = v.x; bidx = base + 0; }
        if (v.y > best) { best = v.y; bidx = base + 1; }
        if (v.z > best) { best = v.z; bidx = base + 2; }
        if (v.w > best) { best = v.w; bidx = base + 3; }
    }
    #pragma unroll
    for (int off = 32; off; off >>= 1) {
        float ov = __shfl_down(best, off);
        int   oi = __shfl_down(bidx, off);
        if (ov > best || (ov == best && oi < bidx)) { best = ov; bidx = oi; }
    }
    if (lane == 0) { ind_f[row] = (float)bidx; ind_i[row] = bidx; }
}

// ---------------- quantize gather + segment-sum scatter --------------------
__global__ void gather_scatter(const float* __restrict__ x,
                               const float* __restrict__ embed,
                               const int* __restrict__ ind,
                               float* __restrict__ quant,
                               float* __restrict__ esum,
                               int* __restrict__ bins) {
    int n = blockIdx.x;
    int k = ind[n];
    int t = threadIdx.x;
    size_t xb = (size_t)n * Dd;
    size_t eb = (size_t)k * Dd;
    float v0 = x[xb + t];
    float v1 = x[xb + t + 256];
    quant[xb + t]       = embed[eb + t];
    quant[xb + t + 256] = embed[eb + t + 256];
    atomicAdd(&esum[eb + t],       v0);
    atomicAdd(&esum[eb + t + 256], v1);
    if (t == 0) atomicAdd(&bins[k], 1);
}

// ---------------- EMA cluster size + laplace total -------------------------
__global__ void finalize1(const float* __restrict__ cs, const int* __restrict__ bins,
                          float* __restrict__ ncs, float* __restrict__ total_ws) {
    __shared__ float red[16];
    int t = threadIdx.x;
    float s = 0.f;
    for (int k = t; k < Kk; k += 1024) {
        float v = cs[k] * DECAY + OMD * (float)bins[k];
        ncs[k] = v;
        s += v;
    }
    #pragma unroll
    for (int off = 32; off; off >>= 1) s += __shfl_down(s, off);
    if ((t & 63) == 0) red[t >> 6] = s;
    __syncthreads();
    if (t == 0) {
        float tot = 0.f;
        #pragma unroll
        for (int i = 0; i < 16; ++i) tot += red[i];
        total_ws[0] = tot;
    }
}

// ---------------- EMA embed_avg + smoothed divide ---------------------------
__global__ void finalize2(const float* __restrict__ ea, const float* __restrict__ esum,
                          const float* __restrict__ ncs, const float* __restrict__ total_ws,
                          float* __restrict__ nea, float* __restrict__ ne) {
    int idx = blockIdx.x * 256 + threadIdx.x;
    float total = total_ws[0];
    int k = idx >> 7;
    float sm = (ncs[k] + EPS) / (total + Kk * EPS) * total;
    float inv = 1.f / sm;
    float4 a = ((const float4*)ea)[idx];
    float4 s = ((const float4*)esum)[idx];
    float4 r;
    r.x = a.x * DECAY + OMD * s.x;
    r.y = a.y * DECAY + OMD * s.y;
    r.z = a.z * DECAY + OMD * s.z;
    r.w = a.w * DECAY + OMD * s.w;
    ((float4*)nea)[idx] = r;
    float4 e;
    e.x = r.x * inv; e.y = r.y * inv; e.z = r.z * inv; e.w = r.w * inv;
    ((float4*)ne)[idx] = e;
}

extern "C" void kernel_launch(void* const* d_in, const int* in_sizes, int n_in,
                              void* d_out, int out_size, void* d_ws, size_t ws_size,
                              hipStream_t stream) {
    const float* x     = (const float*)d_in[0];
    const float* embed = (const float*)d_in[1];
    const float* cs    = (const float*)d_in[2];
    const float* ea    = (const float*)d_in[3];

    float* out     = (float*)d_out;
    float* o_quant = out;
    float* o_ind   = o_quant + (size_t)Nn * Dd;
    float* o_dist  = o_ind + Nn;
    float* o_ncs   = o_dist + (size_t)Nn * Kk;
    float* o_nea   = o_ncs + Kk;
    float* o_ne    = o_nea + (size_t)Kk * Dd;

    // ---- ws layout ----
    size_t xp_elems = (size_t)3 * Nn * Dd;       // bf16
    size_t ep_elems = (size_t)3 * Kk * Dd;
    char* w = (char*)d_ws;
    unsigned short* xp = (unsigned short*)w;                 w += xp_elems * 2;
    unsigned short* epp = (unsigned short*)w;                w += ep_elems * 2;
    float* xsq   = (float*)w;                                w += (size_t)Nn * 4;
    float* esq   = (float*)w;                                w += (size_t)Kk * 4;
    int*   ind_i = (int*)w;                                  w += (size_t)Nn * 4;
    int*   bins  = (int*)w;                                  w += (size_t)Kk * 4;
    float* esum  = (float*)w;                                w += (size_t)Kk * Dd * 4;
    unsigned long long* packed = (unsigned long long*)w;     w += (size_t)Nn * 8;
    float* total = (float*)w;                                w += 256;
    size_t need = (size_t)(w - (char*)d_ws);

    if (ws_size >= need) {
        hipMemsetAsync(bins, 0, (size_t)Kk * 4 + (size_t)Kk * Dd * 4 + (size_t)Nn * 8, stream);

        rows_sq<<<Nn / 4, 256, 0, stream>>>(x, xsq, Nn);
        rows_sq<<<Kk / 4, 256, 0, stream>>>(embed, esq, Kk);

        conv_split<<<(Nn * Dd / 4 + 255) / 256, 256, 0, stream>>>(
            x, xp, xp + (size_t)Nn * Dd, xp + (size_t)2 * Nn * Dd, Nn * Dd / 4);
        conv_split<<<(Kk * Dd / 4 + 255) / 256, 256, 0, stream>>>(
            embed, epp, epp + (size_t)Kk * Dd, epp + (size_t)2 * Kk * Dd, Kk * Dd / 4);

        gemm_split256<<<(Nn / 256) * (Kk / 256), 512, 0, stream>>>(
            xp, epp, xsq, esq, o_dist, packed);

        unpack_argmax<<<Nn / 256, 256, 0, stream>>>(packed, o_ind, ind_i);
    } else {
        float* fxsq  = (float*)d_ws;
        float* fesq  = fxsq + Nn;
        int*   find  = (int*)(fesq + Kk);
        int*   fbins = find + Nn;
        float* fesum = (float*)(fbins + Kk);
        float* ftot  = fesum + (size_t)Kk * Dd;
        xsq = fxsq; esq = fesq; ind_i = find; bins = fbins; esum = fesum; total = ftot;

        hipMemsetAsync(bins, 0, (size_t)(Kk + Kk * Dd) * sizeof(float), stream);
        rows_sq<<<Nn / 4, 256, 0, stream>>>(x, xsq, Nn);
        rows_sq<<<Kk / 4, 256, 0, stream>>>(embed, esq, Kk);
        dim3 g(Nn / BM, Kk / BN);
        gemm_dist<<<g, 256, 0, stream>>>(x, embed, xsq, esq, o_dist);
        argmax_k<<<Nn / 4, 256, 0, stream>>>(o_dist, o_ind, ind_i);
    }

    gather_scatter<<<Nn, 256, 0, stream>>>(x, embed, ind_i, o_quant, esum, bins);
    finalize1<<<1, 1024, 0, stream>>>(cs, bins, o_ncs, total);
    finalize2<<<(Kk * Dd / 4) / 256, 256, 0, stream>>>(ea, esum, o_ncs, total, o_nea, o_ne);
}